// Round 6
// baseline (511.740 us; speedup 1.0000x reference)
//
#include <hip/hip_runtime.h>
#include <stdint.h>

#define NN 4096
#define NEG_SLOPE 0.01f

typedef _Float16 f16x8 __attribute__((ext_vector_type(8)));
typedef float f32x4 __attribute__((ext_vector_type(4)));

// float indices into out: [lslope diag NxN][lintercept N][uslope diag NxN][uintercept N]
#define L_INT  16777216
#define U_DIAG 16781312
#define U_INT  33558528
#define TAIL0  33554432   // slow path: gemm zeroes floats [L_INT, TAIL0)
#define TAIL2  33554432   // fast path: gemm zeroes floats [0, TAIL2)

// async global->LDS: per-lane global addr, LDS dest = wave-uniform base + lane*16
__device__ __forceinline__ void async_ld16(void* lds, const void* g) {
    __builtin_amdgcn_global_load_lds(
        (__attribute__((address_space(1))) const void*)(const void*)g,
        (__attribute__((address_space(3))) void*)lds, 16, 0, 0);
}

// ---------------------------------------------------------------------------
// GEMM M = W2 @ W1 (fp16) with dual row-reduction epilogue:
//   S[j] += sum_n e[n]*|M[j,n]|,  U[j] += sum_n c[n]*M[j,n]
// (verified structure: 128x128 tile, 4 waves, 2-barrier K-loop, ~141 us total,
//  MfmaUtil 48%. DO NOT: 8-phase/256^2 ports (slower twice, R1/R2);
//  last-block-done fusion (R4: __threadfence = buffer_wbl2+buffer_inv per
//  block -> L2 shootdown -> 2x latency regression).)
// R6: diagnostic split -- launched as 4 sequential dispatches of 256 blocks
// (boff = dispatch index) so rocprof's top-5 threshold drops to ~35 us and
// prep becomes visible if it exceeds its roofline. Blocks are independent;
// effective block id = blockIdx.x + 256*boff everywhere.
// Interleaved zero-fill of (64/EVERY)*256 f32x4 per block of d_out on the
// otherwise-idle store pipe. LDS: 128-B rows, fetch-side XOR permutation ->
// SQ_LDS_BANK_CONFLICT == 0.
// ---------------------------------------------------------------------------
template<int EVERY>
__global__ __launch_bounds__(256, 4)
void gemm_SU(const _Float16* __restrict__ Ah, const _Float16* __restrict__ Bt,
             const float* __restrict__ lb0, const float* __restrict__ ub0,
             float* __restrict__ S, float* __restrict__ U,
             f32x4* __restrict__ zbase, int boff) {
    __shared__ _Float16 sA[128][64];   // 16 KB
    __shared__ _Float16 sB[128][64];   // 16 KB
    const int bid = blockIdx.x + (boff << 8);
    const int t = threadIdx.x;
    const int lane = t & 63;
    const int w = t >> 6;
    const int waveRow = w >> 1, waveCol = w & 1;
    const int quad = lane >> 4, l15 = lane & 15, l7 = lane & 7;

    const int bRow = (bid >> 5) * 128;   // output rows j
    const int bCol = (bid & 31) * 128;   // output cols n

    const int rOff = lane >> 3;                 // 8 rows per issue
    const int uG   = (lane & 7) ^ (lane >> 3);  // fetch-side XOR permutation
    const _Float16* gA = Ah + (size_t)(bRow + w * 32 + rOff) * NN + uG * 8;
    const _Float16* gB = Bt + (size_t)(bCol + w * 32 + rOff) * NN + uG * 8;

    f32x4 acc[4][4];
#pragma unroll
    for (int i = 0; i < 4; ++i)
#pragma unroll
        for (int j = 0; j < 4; ++j) acc[i][j] = (f32x4){0.f, 0.f, 0.f, 0.f};

    const f32x4 zv = (f32x4){0.f, 0.f, 0.f, 0.f};
    const int NZB = (64 / EVERY) * 256;   // f32x4 per block

    for (int kt = 0; kt < NN / 64; ++kt) {
        const int k0 = kt * 64;
        __syncthreads();   // previous tile's frag reads complete
#pragma unroll
        for (int i = 0; i < 4; ++i) {
            async_ld16(&sA[w * 32 + i * 8][0], gA + (size_t)(i * 8) * NN + k0);
            async_ld16(&sB[w * 32 + i * 8][0], gB + (size_t)(i * 8) * NN + k0);
        }
        __syncthreads();   // vmcnt(0) drained at barrier -> LDS valid

#pragma unroll
        for (int s = 0; s < 2; ++s) {
            f16x8 af[4];
#pragma unroll
            for (int fr = 0; fr < 4; ++fr) {
                const int r = waveRow * 64 + fr * 16 + l15;   // r&7 == l7
                af[fr] = *(const f16x8*)&sA[r][((s * 4 + quad) ^ l7) * 8];
            }
#pragma unroll
            for (int fc = 0; fc < 4; ++fc) {
                const int c = waveCol * 64 + fc * 16 + l15;
                const f16x8 bf = *(const f16x8*)&sB[c][((s * 4 + quad) ^ l7) * 8];
#pragma unroll
                for (int fr = 0; fr < 4; ++fr)
                    acc[fr][fc] = __builtin_amdgcn_mfma_f32_16x16x32_f16(af[fr], bf, acc[fr][fc], 0, 0, 0);
            }
        }

        // interleaved zero-fill of d_out, hidden under MFMA
        if ((kt & (EVERY - 1)) == 0) {
            const int zi = kt / EVERY;
            __builtin_nontemporal_store(zv,
                zbase + (size_t)bid * NZB + zi * 256 + t);
        }
    }

    // epilogue: dual weighted row-reduction over this block's 128 cols
    float ev[4], cv[4];
#pragma unroll
    for (int fc = 0; fc < 4; ++fc) {
        const int col = bCol + waveCol * 64 + fc * 16 + l15;
        const float l = lb0[col], u_ = ub0[col];
        ev[fc] = 0.5f * (u_ - l);
        cv[fc] = 0.5f * (u_ + l);
    }
#pragma unroll
    for (int fr = 0; fr < 4; ++fr) {
#pragma unroll
        for (int r = 0; r < 4; ++r) {
            float sv = 0.f, uv = 0.f;
#pragma unroll
            for (int fc = 0; fc < 4; ++fc) {
                const float m = acc[fr][fc][r];
                sv += ev[fc] * fabsf(m);
                uv += cv[fc] * m;
            }
            // C/D layout: col = lane&15, row = quad*4 + r (m89/m91)
#pragma unroll
            for (int mk = 1; mk < 16; mk <<= 1) {
                sv += __shfl_xor(sv, mk, 64);
                uv += __shfl_xor(uv, mk, 64);
            }
            if (l15 == 0) {
                const int row = bRow + waveRow * 64 + fr * 16 + quad * 4 + r;
                atomicAdd(&S[row], sv);
                atomicAdd(&U[row], uv);
            }
        }
    }
}

// ---------------------------------------------------------------------------
// prep (fused), 5120 blocks x 256:
//  blocks 0..1023:  wave-per-row x4: Ah[j,:]=fp16(W2[j,:]); cj[j]=W2[j,:].b1+b2[j];
//                   S[j]=U[j]=0
//  blocks 1024..5119: 64x64 transpose tile of W1 -> Bt fp16 (Bt[n][k]=W1[k][n])
// ---------------------------------------------------------------------------
__global__ __launch_bounds__(256)
void prep(const float* __restrict__ W2, const float* __restrict__ W1,
          const float* __restrict__ b1, const float* __restrict__ b2,
          _Float16* __restrict__ Ah, _Float16* __restrict__ Bt,
          float* __restrict__ cj, float* __restrict__ S, float* __restrict__ U) {
    __shared__ float sT[64][65];
    const int b = blockIdx.x;
    const int t = threadIdx.x;
    if (b < 1024) {
        const int lane = t & 63;
        const int w = t >> 6;
        const int j = b * 4 + w;
        const float* row = W2 + (size_t)j * NN;
        _Float16* orow = Ah + (size_t)j * NN;
        float d1 = 0.f;
#pragma unroll
        for (int q = 0; q < 8; ++q) {
            const int i = q * 512 + lane * 8;
            const float4 a0 = *(const float4*)&row[i];
            const float4 a1 = *(const float4*)&row[i + 4];
            const float4 c0 = *(const float4*)&b1[i];
            const float4 c1 = *(const float4*)&b1[i + 4];
            d1 += a0.x * c0.x + a0.y * c0.y + a0.z * c0.z + a0.w * c0.w;
            d1 += a1.x * c1.x + a1.y * c1.y + a1.z * c1.z + a1.w * c1.w;
            f16x8 h;
            h[0] = (_Float16)a0.x; h[1] = (_Float16)a0.y;
            h[2] = (_Float16)a0.z; h[3] = (_Float16)a0.w;
            h[4] = (_Float16)a1.x; h[5] = (_Float16)a1.y;
            h[6] = (_Float16)a1.z; h[7] = (_Float16)a1.w;
            *(f16x8*)&orow[i] = h;
        }
#pragma unroll
        for (int mk = 1; mk < 64; mk <<= 1) d1 += __shfl_xor(d1, mk, 64);
        if (lane == 0) {
            cj[j] = d1 + b2[j];
            S[j] = 0.f;
            U[j] = 0.f;
        }
    } else {
        const int tile = b - 1024;
        const int bi = (tile & 63) * 64;   // W1 row range (contraction k)
        const int bn = (tile >> 6) * 64;   // W1 col range (n)
        const int r = t >> 4, c4 = (t & 15) * 4;
#pragma unroll
        for (int p = 0; p < 4; ++p) {
            const float4 a = *(const float4*)&W1[(size_t)(bi + r + p * 16) * NN + bn + c4];
            sT[r + p * 16][c4 + 0] = a.x;
            sT[r + p * 16][c4 + 1] = a.y;
            sT[r + p * 16][c4 + 2] = a.z;
            sT[r + p * 16][c4 + 3] = a.w;
        }
        __syncthreads();
        // write side: lane handles 8 contiguous k (16 B); sT bank stride 65%32=1
        // -> bank = (k + n) & 31, 2-way over the wave = free
        const int k8 = (t & 7) * 8;
#pragma unroll
        for (int p = 0; p < 2; ++p) {
            const int n = (t >> 3) + p * 32;
            f16x8 h;
#pragma unroll
            for (int e = 0; e < 8; ++e) h[e] = (_Float16)sT[k8 + e][n];
            *(f16x8*)&Bt[(size_t)(bn + n) * NN + bi + k8] = h;
        }
    }
}

// ---- DeepPoly relaxation helpers ----
__device__ __forceinline__ void get_lub(int j, const float* S, const float* U,
                                        const float* cj, float& lb, float& ub) {
    const float base = U[j] + cj[j], Sv = S[j];
    lb = base - Sv;
    ub = base + Sv;
}
__device__ __forceinline__ float slope_of(float lb, float ub) {
    float s = (ub - lb * NEG_SLOPE) / (ub - lb);
    if (!(s == s)) s = 0.f;
    return s;
}
__device__ __forceinline__ float uslope_of(float lb, float ub) {
    const bool below = (ub <= 0.f), above = (lb >= 0.f);
    return (!(below || above)) ? slope_of(lb, ub) : (below ? NEG_SLOPE : 1.f);
}
__device__ __forceinline__ float lslope_of(float lb, float ub, float raw) {
    const float alpha = 1.f / (1.f + expf(-raw));
    const bool below = (ub <= 0.f), above = (lb >= 0.f);
    const bool crossing = !(below || above);
    const float v1 = below ? NEG_SLOPE : 1.f;
    const float v2 = crossing ? NEG_SLOPE : v1;
    return alpha * v1 + (1.f - alpha) * v2;
}

// ---------------------------------------------------------------------------
// finish_fast, grid 18 (gemm zeroed floats [0, TAIL2)):
//  block 0:      zero tail floats [TAIL2, U_INT), set uslope diag j=4095
//  blocks 1..16: scattered diag writes: lslope all j, uslope j<4095
//  block 17:     uintercept row
// ---------------------------------------------------------------------------
__global__ __launch_bounds__(256)
void finish_fast(const float* __restrict__ S, const float* __restrict__ U,
                 const float* __restrict__ cj, const float* __restrict__ ra,
                 float* __restrict__ out) {
    const int b = blockIdx.x;
    const int t = threadIdx.x;
    if (b == 0) {
        f32x4* p = (f32x4*)(out + TAIL2);
#pragma unroll
        for (int q = 0; q < 4; ++q) {
            const int i4 = t + q * 256;
            f32x4 z = (f32x4){0.f, 0.f, 0.f, 0.f};
            if (i4 == 1023) {
                float lb, ub;
                get_lub(4095, S, U, cj, lb, ub);
                z[3] = uslope_of(lb, ub);   // U_DIAG + 4095*4097 == U_INT-1
            }
            __builtin_nontemporal_store(z, &p[i4]);
        }
    } else if (b <= 16) {
        const int j = (b - 1) * 256 + t;
        float lb, ub;
        get_lub(j, S, U, cj, lb, ub);
        out[(size_t)j * (NN + 1)] = lslope_of(lb, ub, ra[j]);
        if (j < 4095)
            out[U_DIAG + (size_t)j * (NN + 1)] = uslope_of(lb, ub);
    } else {
#pragma unroll
        for (int q = 0; q < 16; ++q) {
            const int j = t + q * 256;
            float lb, ub;
            get_lub(j, S, U, cj, lb, ub);
            const bool below = (ub <= 0.f), above = (lb >= 0.f);
            const bool crossing = !(below || above);
            out[U_INT + j] = crossing ? (1.f - slope_of(lb, ub)) * ub : 0.f;
        }
    }
}

// ---------------------------------------------------------------------------
// finish_slow, grid 4114 (fallback: Ah/Bt lived in out[0,64MB); gemm zeroed
// [L_INT, TAIL0)).
// ---------------------------------------------------------------------------
__global__ __launch_bounds__(256)
void finish_slow(const float* __restrict__ S, const float* __restrict__ U,
                 const float* __restrict__ cj, const float* __restrict__ ra,
                 float* __restrict__ out) {
    const int b = blockIdx.x;
    const int t = threadIdx.x;
    if (b < 4096) {
        const int j = b;
        float lb, ub;
        get_lub(j, S, U, cj, lb, ub);
        const float ls = lslope_of(lb, ub, ra[j]);
        f32x4* rowp = (f32x4*)(out + (size_t)j * NN);
        const int dq = j >> 2, dr = j & 3;
#pragma unroll
        for (int q = 0; q < 4; ++q) {
            const int i4 = t + q * 256;
            f32x4 z = (f32x4){0.f, 0.f, 0.f, 0.f};
            if (i4 == dq) z[dr] = ls;
            __builtin_nontemporal_store(z, &rowp[i4]);
        }
    } else if (b < 4112) {
        const int j = (b - 4096) * 256 + t;
        if (j < 4095) {
            float lb, ub;
            get_lub(j, S, U, cj, lb, ub);
            out[U_DIAG + (size_t)j * NN + j] = uslope_of(lb, ub);
        }
    } else if (b == 4112) {
        f32x4* p = (f32x4*)(out + TAIL0);
#pragma unroll
        for (int q = 0; q < 4; ++q) {
            const int i4 = t + q * 256;
            f32x4 z = (f32x4){0.f, 0.f, 0.f, 0.f};
            if (i4 == 1023) {
                float lb, ub;
                get_lub(4095, S, U, cj, lb, ub);
                z[3] = uslope_of(lb, ub);
            }
            __builtin_nontemporal_store(z, &p[i4]);
        }
    } else {
#pragma unroll
        for (int q = 0; q < 16; ++q) {
            const int j = t + q * 256;
            float lb, ub;
            get_lub(j, S, U, cj, lb, ub);
            const bool below = (ub <= 0.f), above = (lb >= 0.f);
            const bool crossing = !(below || above);
            out[U_INT + j] = crossing ? (1.f - slope_of(lb, ub)) * ub : 0.f;
        }
    }
}

extern "C" void kernel_launch(void* const* d_in, const int* in_sizes, int n_in,
                              void* d_out, int out_size, void* d_ws, size_t ws_size,
                              hipStream_t stream) {
    const float* lb0 = (const float*)d_in[0];
    const float* ub0 = (const float*)d_in[1];
    const float* W1  = (const float*)d_in[2];
    const float* b1  = (const float*)d_in[3];
    const float* W2  = (const float*)d_in[4];
    const float* b2  = (const float*)d_in[5];
    const float* ra  = (const float*)d_in[6];
    float* out = (float*)d_out;

    float* S  = (float*)d_ws;   // [N] zeroed by prep
    float* U  = S + NN;         // [N] zeroed by prep
    float* cj = U + NN;         // [N]

    const size_t need = 3 * (size_t)NN * sizeof(float)
                      + 2 * (size_t)NN * NN * sizeof(_Float16);
    const bool fast = ws_size >= need;   // ws_size is constant per session

    if (fast) {
        // Ah/Bt in d_ws -> gemm zero-fills the whole diag area of d_out.
        // R6 diagnostic: gemm as 4 sequential 256-block dispatches so the
        // rocprof top-5 threshold drops to ~35 us (prep visibility).
        _Float16* Ah = (_Float16*)(cj + NN);
        _Float16* Bt = Ah + (size_t)NN * NN;
        prep<<<dim3(5120), dim3(256), 0, stream>>>(W2, W1, b1, b2, Ah, Bt,
                                                   cj, S, U);
        for (int boff = 0; boff < 4; ++boff)
            gemm_SU<2><<<dim3(256), dim3(256), 0, stream>>>(
                Ah, Bt, lb0, ub0, S, U, (f32x4*)out, boff);
        finish_fast<<<dim3(18), dim3(256), 0, stream>>>(S, U, cj, ra, out);
    } else {
        // fallback: Ah/Bt in d_out's first 64 MB
        _Float16* Ah = (_Float16*)d_out;
        _Float16* Bt = Ah + (size_t)NN * NN;
        prep<<<dim3(5120), dim3(256), 0, stream>>>(W2, W1, b1, b2, Ah, Bt,
                                                   cj, S, U);
        gemm_SU<4><<<dim3(1024), dim3(256), 0, stream>>>(
            Ah, Bt, lb0, ub0, S, U, (f32x4*)(out + L_INT), 0);
        finish_slow<<<dim3(4114), dim3(256), 0, stream>>>(S, U, cj, ra, out);
    }
}

// Round 7
// 375.519 us; speedup vs baseline: 1.3628x; 1.3628x over previous
//
#include <hip/hip_runtime.h>
#include <stdint.h>

#define NN 4096
#define NEG_SLOPE 0.01f

typedef _Float16 f16x8 __attribute__((ext_vector_type(8)));
typedef float f32x4 __attribute__((ext_vector_type(4)));

// float indices into out: [lslope diag NxN][lintercept N][uslope diag NxN][uintercept N]
#define L_INT  16777216
#define U_DIAG 16781312
#define U_INT  33558528
#define TAIL0  33554432   // slow path: gemm zeroes floats [L_INT, TAIL0)
#define TAIL2  33554432   // fast path: gemm zeroes floats [0, TAIL2)

// async global->LDS: per-lane global addr, LDS dest = wave-uniform base + lane*16
__device__ __forceinline__ void async_ld16(void* lds, const void* g) {
    __builtin_amdgcn_global_load_lds(
        (__attribute__((address_space(1))) const void*)(const void*)g,
        (__attribute__((address_space(3))) void*)lds, 16, 0, 0);
}

// ---------------------------------------------------------------------------
// GEMM M = W2 @ W1 (fp16) with dual row-reduction epilogue:
//   S[j] += sum_n e[n]*|M[j,n]|,  U[j] += sum_n c[n]*M[j,n]
// (verified structure: 128x128 tile, 4 waves, 2-barrier K-loop, ~140 us,
//  MfmaUtil 48%, 960 TF ~= the m97-structure ceiling for this op.
//  DO NOT: 8-phase/256^2 ports (slower, R1/R2 -- 1 block/CU kills the
//  cross-block TLP this 2-barrier loop relies on; R6 split showed the same);
//  last-block-done fusion (R4: __threadfence = buffer_wbl2+buffer_inv per
//  block -> L2 shootdown -> 2x latency regression);
//  multi-dispatch gemm split (R6: +134 us, same occupancy mechanism).)
// Interleaved zero-fill of (64/EVERY)*256 f32x4 per block of d_out on the
// otherwise-idle store pipe (~+3 us hidden). LDS: 128-B rows, fetch-side XOR
// permutation -> SQ_LDS_BANK_CONFLICT == 0.
// ---------------------------------------------------------------------------
template<int EVERY>
__global__ __launch_bounds__(256, 4)
void gemm_SU(const _Float16* __restrict__ Ah, const _Float16* __restrict__ Bt,
             const float* __restrict__ lb0, const float* __restrict__ ub0,
             float* __restrict__ S, float* __restrict__ U,
             f32x4* __restrict__ zbase) {
    __shared__ _Float16 sA[128][64];   // 16 KB
    __shared__ _Float16 sB[128][64];   // 16 KB
    const int t = threadIdx.x;
    const int lane = t & 63;
    const int w = t >> 6;
    const int waveRow = w >> 1, waveCol = w & 1;
    const int quad = lane >> 4, l15 = lane & 15, l7 = lane & 7;

    const int bRow = (blockIdx.x >> 5) * 128;   // output rows j
    const int bCol = (blockIdx.x & 31) * 128;   // output cols n

    const int rOff = lane >> 3;                 // 8 rows per issue
    const int uG   = (lane & 7) ^ (lane >> 3);  // fetch-side XOR permutation
    const _Float16* gA = Ah + (size_t)(bRow + w * 32 + rOff) * NN + uG * 8;
    const _Float16* gB = Bt + (size_t)(bCol + w * 32 + rOff) * NN + uG * 8;

    f32x4 acc[4][4];
#pragma unroll
    for (int i = 0; i < 4; ++i)
#pragma unroll
        for (int j = 0; j < 4; ++j) acc[i][j] = (f32x4){0.f, 0.f, 0.f, 0.f};

    const f32x4 zv = (f32x4){0.f, 0.f, 0.f, 0.f};
    const int NZB = (64 / EVERY) * 256;   // f32x4 per block

    for (int kt = 0; kt < NN / 64; ++kt) {
        const int k0 = kt * 64;
        __syncthreads();   // previous tile's frag reads complete
#pragma unroll
        for (int i = 0; i < 4; ++i) {
            async_ld16(&sA[w * 32 + i * 8][0], gA + (size_t)(i * 8) * NN + k0);
            async_ld16(&sB[w * 32 + i * 8][0], gB + (size_t)(i * 8) * NN + k0);
        }
        __syncthreads();   // vmcnt(0) drained at barrier -> LDS valid

#pragma unroll
        for (int s = 0; s < 2; ++s) {
            f16x8 af[4];
#pragma unroll
            for (int fr = 0; fr < 4; ++fr) {
                const int r = waveRow * 64 + fr * 16 + l15;   // r&7 == l7
                af[fr] = *(const f16x8*)&sA[r][((s * 4 + quad) ^ l7) * 8];
            }
#pragma unroll
            for (int fc = 0; fc < 4; ++fc) {
                const int c = waveCol * 64 + fc * 16 + l15;
                const f16x8 bf = *(const f16x8*)&sB[c][((s * 4 + quad) ^ l7) * 8];
#pragma unroll
                for (int fr = 0; fr < 4; ++fr)
                    acc[fr][fc] = __builtin_amdgcn_mfma_f32_16x16x32_f16(af[fr], bf, acc[fr][fc], 0, 0, 0);
            }
        }

        // interleaved zero-fill of d_out, hidden under MFMA
        if ((kt & (EVERY - 1)) == 0) {
            const int zi = kt / EVERY;
            __builtin_nontemporal_store(zv,
                zbase + (size_t)blockIdx.x * NZB + zi * 256 + t);
        }
    }

    // epilogue: dual weighted row-reduction over this block's 128 cols
    float ev[4], cv[4];
#pragma unroll
    for (int fc = 0; fc < 4; ++fc) {
        const int col = bCol + waveCol * 64 + fc * 16 + l15;
        const float l = lb0[col], u_ = ub0[col];
        ev[fc] = 0.5f * (u_ - l);
        cv[fc] = 0.5f * (u_ + l);
    }
#pragma unroll
    for (int fr = 0; fr < 4; ++fr) {
#pragma unroll
        for (int r = 0; r < 4; ++r) {
            float sv = 0.f, uv = 0.f;
#pragma unroll
            for (int fc = 0; fc < 4; ++fc) {
                const float m = acc[fr][fc][r];
                sv += ev[fc] * fabsf(m);
                uv += cv[fc] * m;
            }
            // C/D layout: col = lane&15, row = quad*4 + r (m89/m91)
#pragma unroll
            for (int mk = 1; mk < 16; mk <<= 1) {
                sv += __shfl_xor(sv, mk, 64);
                uv += __shfl_xor(uv, mk, 64);
            }
            if (l15 == 0) {
                const int row = bRow + waveRow * 64 + fr * 16 + quad * 4 + r;
                atomicAdd(&S[row], sv);
                atomicAdd(&U[row], uv);
            }
        }
    }
}

// ---------------------------------------------------------------------------
// prep (fused), 5120 blocks x 256:
//  blocks 0..1023:  wave-per-row x4: Ah[j,:]=fp16(W2[j,:]); cj[j]=W2[j,:].b1+b2[j];
//                   S[j]=U[j]=0
//  blocks 1024..5119: 64x64 transpose tile of W1 -> Bt fp16 (Bt[n][k]=W1[k][n])
// (measured: prep structure-insensitive across R0/R3/R5 variants (<1 us delta)
//  and < 81 us total (R6 visibility bound) -> at/near its memory floor.)
// ---------------------------------------------------------------------------
__global__ __launch_bounds__(256)
void prep(const float* __restrict__ W2, const float* __restrict__ W1,
          const float* __restrict__ b1, const float* __restrict__ b2,
          _Float16* __restrict__ Ah, _Float16* __restrict__ Bt,
          float* __restrict__ cj, float* __restrict__ S, float* __restrict__ U) {
    __shared__ float sT[64][65];
    const int b = blockIdx.x;
    const int t = threadIdx.x;
    if (b < 1024) {
        const int lane = t & 63;
        const int w = t >> 6;
        const int j = b * 4 + w;
        const float* row = W2 + (size_t)j * NN;
        _Float16* orow = Ah + (size_t)j * NN;
        float d1 = 0.f;
#pragma unroll
        for (int q = 0; q < 8; ++q) {
            const int i = q * 512 + lane * 8;
            const float4 a0 = *(const float4*)&row[i];
            const float4 a1 = *(const float4*)&row[i + 4];
            const float4 c0 = *(const float4*)&b1[i];
            const float4 c1 = *(const float4*)&b1[i + 4];
            d1 += a0.x * c0.x + a0.y * c0.y + a0.z * c0.z + a0.w * c0.w;
            d1 += a1.x * c1.x + a1.y * c1.y + a1.z * c1.z + a1.w * c1.w;
            f16x8 h;
            h[0] = (_Float16)a0.x; h[1] = (_Float16)a0.y;
            h[2] = (_Float16)a0.z; h[3] = (_Float16)a0.w;
            h[4] = (_Float16)a1.x; h[5] = (_Float16)a1.y;
            h[6] = (_Float16)a1.z; h[7] = (_Float16)a1.w;
            *(f16x8*)&orow[i] = h;
        }
#pragma unroll
        for (int mk = 1; mk < 64; mk <<= 1) d1 += __shfl_xor(d1, mk, 64);
        if (lane == 0) {
            cj[j] = d1 + b2[j];
            S[j] = 0.f;
            U[j] = 0.f;
        }
    } else {
        const int tile = b - 1024;
        const int bi = (tile & 63) * 64;   // W1 row range (contraction k)
        const int bn = (tile >> 6) * 64;   // W1 col range (n)
        const int r = t >> 4, c4 = (t & 15) * 4;
#pragma unroll
        for (int p = 0; p < 4; ++p) {
            const float4 a = *(const float4*)&W1[(size_t)(bi + r + p * 16) * NN + bn + c4];
            sT[r + p * 16][c4 + 0] = a.x;
            sT[r + p * 16][c4 + 1] = a.y;
            sT[r + p * 16][c4 + 2] = a.z;
            sT[r + p * 16][c4 + 3] = a.w;
        }
        __syncthreads();
        // write side: lane handles 8 contiguous k (16 B); sT bank stride 65%32=1
        // -> bank = (k + n) & 31, 2-way over the wave = free
        const int k8 = (t & 7) * 8;
#pragma unroll
        for (int p = 0; p < 2; ++p) {
            const int n = (t >> 3) + p * 32;
            f16x8 h;
#pragma unroll
            for (int e = 0; e < 8; ++e) h[e] = (_Float16)sT[k8 + e][n];
            *(f16x8*)&Bt[(size_t)(bn + n) * NN + bi + k8] = h;
        }
    }
}

// ---- DeepPoly relaxation helpers ----
__device__ __forceinline__ void get_lub(int j, const float* S, const float* U,
                                        const float* cj, float& lb, float& ub) {
    const float base = U[j] + cj[j], Sv = S[j];
    lb = base - Sv;
    ub = base + Sv;
}
__device__ __forceinline__ float slope_of(float lb, float ub) {
    float s = (ub - lb * NEG_SLOPE) / (ub - lb);
    if (!(s == s)) s = 0.f;
    return s;
}
__device__ __forceinline__ float uslope_of(float lb, float ub) {
    const bool below = (ub <= 0.f), above = (lb >= 0.f);
    return (!(below || above)) ? slope_of(lb, ub) : (below ? NEG_SLOPE : 1.f);
}
__device__ __forceinline__ float lslope_of(float lb, float ub, float raw) {
    const float alpha = 1.f / (1.f + expf(-raw));
    const bool below = (ub <= 0.f), above = (lb >= 0.f);
    const bool crossing = !(below || above);
    const float v1 = below ? NEG_SLOPE : 1.f;
    const float v2 = crossing ? NEG_SLOPE : v1;
    return alpha * v1 + (1.f - alpha) * v2;
}

// ---------------------------------------------------------------------------
// finish_fast, grid 18 (gemm zeroed floats [0, TAIL2)):
//  block 0:      zero tail floats [TAIL2, U_INT), set uslope diag j=4095
//  blocks 1..16: scattered diag writes: lslope all j, uslope j<4095
//  block 17:     uintercept row
// ---------------------------------------------------------------------------
__global__ __launch_bounds__(256)
void finish_fast(const float* __restrict__ S, const float* __restrict__ U,
                 const float* __restrict__ cj, const float* __restrict__ ra,
                 float* __restrict__ out) {
    const int b = blockIdx.x;
    const int t = threadIdx.x;
    if (b == 0) {
        f32x4* p = (f32x4*)(out + TAIL2);
#pragma unroll
        for (int q = 0; q < 4; ++q) {
            const int i4 = t + q * 256;
            f32x4 z = (f32x4){0.f, 0.f, 0.f, 0.f};
            if (i4 == 1023) {
                float lb, ub;
                get_lub(4095, S, U, cj, lb, ub);
                z[3] = uslope_of(lb, ub);   // U_DIAG + 4095*4097 == U_INT-1
            }
            __builtin_nontemporal_store(z, &p[i4]);
        }
    } else if (b <= 16) {
        const int j = (b - 1) * 256 + t;
        float lb, ub;
        get_lub(j, S, U, cj, lb, ub);
        out[(size_t)j * (NN + 1)] = lslope_of(lb, ub, ra[j]);
        if (j < 4095)
            out[U_DIAG + (size_t)j * (NN + 1)] = uslope_of(lb, ub);
    } else {
#pragma unroll
        for (int q = 0; q < 16; ++q) {
            const int j = t + q * 256;
            float lb, ub;
            get_lub(j, S, U, cj, lb, ub);
            const bool below = (ub <= 0.f), above = (lb >= 0.f);
            const bool crossing = !(below || above);
            out[U_INT + j] = crossing ? (1.f - slope_of(lb, ub)) * ub : 0.f;
        }
    }
}

// ---------------------------------------------------------------------------
// finish_slow, grid 4114 (fallback: Ah/Bt lived in out[0,64MB); gemm zeroed
// [L_INT, TAIL0)).
// ---------------------------------------------------------------------------
__global__ __launch_bounds__(256)
void finish_slow(const float* __restrict__ S, const float* __restrict__ U,
                 const float* __restrict__ cj, const float* __restrict__ ra,
                 float* __restrict__ out) {
    const int b = blockIdx.x;
    const int t = threadIdx.x;
    if (b < 4096) {
        const int j = b;
        float lb, ub;
        get_lub(j, S, U, cj, lb, ub);
        const float ls = lslope_of(lb, ub, ra[j]);
        f32x4* rowp = (f32x4*)(out + (size_t)j * NN);
        const int dq = j >> 2, dr = j & 3;
#pragma unroll
        for (int q = 0; q < 4; ++q) {
            const int i4 = t + q * 256;
            f32x4 z = (f32x4){0.f, 0.f, 0.f, 0.f};
            if (i4 == dq) z[dr] = ls;
            __builtin_nontemporal_store(z, &rowp[i4]);
        }
    } else if (b < 4112) {
        const int j = (b - 4096) * 256 + t;
        if (j < 4095) {
            float lb, ub;
            get_lub(j, S, U, cj, lb, ub);
            out[U_DIAG + (size_t)j * NN + j] = uslope_of(lb, ub);
        }
    } else if (b == 4112) {
        f32x4* p = (f32x4*)(out + TAIL0);
#pragma unroll
        for (int q = 0; q < 4; ++q) {
            const int i4 = t + q * 256;
            f32x4 z = (f32x4){0.f, 0.f, 0.f, 0.f};
            if (i4 == 1023) {
                float lb, ub;
                get_lub(4095, S, U, cj, lb, ub);
                z[3] = uslope_of(lb, ub);
            }
            __builtin_nontemporal_store(z, &p[i4]);
        }
    } else {
#pragma unroll
        for (int q = 0; q < 16; ++q) {
            const int j = t + q * 256;
            float lb, ub;
            get_lub(j, S, U, cj, lb, ub);
            const bool below = (ub <= 0.f), above = (lb >= 0.f);
            const bool crossing = !(below || above);
            out[U_INT + j] = crossing ? (1.f - slope_of(lb, ub)) * ub : 0.f;
        }
    }
}

extern "C" void kernel_launch(void* const* d_in, const int* in_sizes, int n_in,
                              void* d_out, int out_size, void* d_ws, size_t ws_size,
                              hipStream_t stream) {
    const float* lb0 = (const float*)d_in[0];
    const float* ub0 = (const float*)d_in[1];
    const float* W1  = (const float*)d_in[2];
    const float* b1  = (const float*)d_in[3];
    const float* W2  = (const float*)d_in[4];
    const float* b2  = (const float*)d_in[5];
    const float* ra  = (const float*)d_in[6];
    float* out = (float*)d_out;

    float* S  = (float*)d_ws;   // [N] zeroed by prep
    float* U  = S + NN;         // [N] zeroed by prep
    float* cj = U + NN;         // [N]

    const size_t need = 3 * (size_t)NN * sizeof(float)
                      + 2 * (size_t)NN * NN * sizeof(_Float16);
    const bool fast = ws_size >= need;   // ws_size is constant per session

    if (fast) {
        // Ah/Bt in d_ws -> gemm zero-fills the whole diag area of d_out
        _Float16* Ah = (_Float16*)(cj + NN);
        _Float16* Bt = Ah + (size_t)NN * NN;
        prep<<<dim3(5120), dim3(256), 0, stream>>>(W2, W1, b1, b2, Ah, Bt,
                                                   cj, S, U);
        gemm_SU<2><<<dim3(1024), dim3(256), 0, stream>>>(Ah, Bt, lb0, ub0, S, U,
                                                         (f32x4*)out);
        finish_fast<<<dim3(18), dim3(256), 0, stream>>>(S, U, cj, ra, out);
    } else {
        // fallback: Ah/Bt in d_out's first 64 MB
        _Float16* Ah = (_Float16*)d_out;
        _Float16* Bt = Ah + (size_t)NN * NN;
        prep<<<dim3(5120), dim3(256), 0, stream>>>(W2, W1, b1, b2, Ah, Bt,
                                                   cj, S, U);
        gemm_SU<4><<<dim3(1024), dim3(256), 0, stream>>>(Ah, Bt, lb0, ub0, S, U,
                                                         (f32x4*)(out + L_INT));
        finish_slow<<<dim3(4114), dim3(256), 0, stream>>>(S, U, cj, ra, out);
    }
}